// Round 23
// baseline (93.236 us; speedup 1.0000x reference)
//
#include <hip/hip_runtime.h>
#include <math.h>

#define NN    4096
#define KK    20
#define QQ    4                 // query points per lane (per wave)
#define WAVES 4
#define BLK   (WAVES*64)        // 256 threads
#define PPB   (WAVES*QQ)        // 16 points per block
#define PIT   16                // pair-iterations per phase (2 pairs/iter)
#define CAP   56                // per-point candidate capacity
#define BPB   (NN/PPB)          // 256 blocks per batch
#define BB    8

typedef float f32x4 __attribute__((ext_vector_type(4)));
typedef float f32x2 __attribute__((ext_vector_type(2)));

__device__ __forceinline__ unsigned fkey(float f) {  // monotone float->uint
  unsigned u = __float_as_uint(f);
  return u ^ ((unsigned)((int)u >> 31) | 0x80000000u);
}
__device__ __forceinline__ float fkey_inv(unsigned k) {
  unsigned u = (k & 0x80000000u) ? (k ^ 0x80000000u) : ~k;
  return __uint_as_float(u);
}

// one thread per point-PAIR: AoS table (feature) + pair-interleaved (scan)
__global__ void prep_kernel(const float* __restrict__ x,
                            float4* __restrict__ ws4,
                            f32x4* __restrict__ wspk) {
  const int p = blockIdx.x * 256 + threadIdx.x;        // 16384 pairs
  const float* s = x + (size_t)p * 6;
  const float x0 = s[0], y0 = s[1], z0 = s[2];
  const float x1 = s[3], y1 = s[4], z1 = s[5];
  const float w0 = fmaf(z0, z0, fmaf(y0, y0, x0 * x0));
  const float w1 = fmaf(z1, z1, fmaf(y1, y1, x1 * x1));
  ws4[2 * p]     = make_float4(x0, y0, z0, w0);
  ws4[2 * p + 1] = make_float4(x1, y1, z1, w1);
  wspk[2 * p]     = (f32x4){x0, x1, y0, y1};
  wspk[2 * p + 1] = (f32x4){z0, z1, w0, w1};
}

template<bool WS>
__global__ __launch_bounds__(BLK, 8)
void edgeconv_kernel(const float* __restrict__ x,
                     const float4* __restrict__ ws4,
                     const f32x4* __restrict__ wspk,
                     const float* __restrict__ W,
                     const float* __restrict__ bias,
                     float* __restrict__ out) {
  __shared__ float2 cand[PPB][CAP + 1];                // 7.3 KB (d, j-bits)
  __shared__ int    jkeep[PPB][21];                    // 1.3 KB
  __shared__ int    pc[PPB];
  __shared__ int    pk[PPB];

  const int tid  = threadIdx.x;
  const int lane = tid & 63;
  const int w    = tid >> 6;
  // batch-per-CU swizzle (validated r18/r22: FETCH 6.3 -> 1.0 MB)
  const int bb   = blockIdx.x % BB;
  const int blk  = blockIdx.x / BB;
  const int base = bb * NN;
  const int g0   = w * QQ;                 // wave's first point group
  const int myp0 = blk * PPB + g0;

  // packed query coeffs: d' = |xj|^2 - 2*xi.xj (order-preserving per point;
  // self value is the strict global minimum and rides along)
  f32x2 nxp[QQ], nyp[QQ], nzp[QQ];
  #pragma unroll
  for (int q = 0; q < QQ; ++q) {
    const float* p = x + (size_t)(base + myp0 + q) * 3;
    const float a = -2.f * p[0], b = -2.f * p[1], c = -2.f * p[2];
    nxp[q] = (f32x2){a, a}; nyp[q] = (f32x2){b, b}; nzp[q] = (f32x2){c, c};
  }

  if (tid < PPB) { pc[tid] = 0; pk[tid] = 0; }
  __syncthreads();

  // pair loader: A=(x0,x1,y0,y1), Bv=(z0,z1,w0,w1); identical fma chain in
  // both paths -> bit-identical d'
  auto ldpair = [&](int pr, f32x4& A, f32x4& Bv) {
    if constexpr (WS) {
      A  = wspk[base + (pr << 1)];
      Bv = wspk[base + (pr << 1) + 1];
    } else {
      const float* s = x + ((size_t)base + ((size_t)pr << 1)) * 3;
      const float x0 = s[0], y0 = s[1], z0 = s[2];
      const float x1 = s[3], y1 = s[4], z1 = s[5];
      A  = (f32x4){x0, x1, y0, y1};
      Bv = (f32x4){z0, z1, fmaf(z0, z0, fmaf(y0, y0, x0 * x0)),
                           fmaf(z1, z1, fmaf(y1, y1, x1 * x1))};
    }
  };
  // AoS point loader (feature phase)
  auto ldp = [&](int j) -> float4 {
    if constexpr (WS) {
      return ws4[base + j];
    } else {
      const float* p = x + (size_t)(base + j) * 3;
      const float a = p[0], b = p[1], c = p[2];
      return make_float4(a, b, c, fmaf(c, c, fmaf(b, b, a * a)));
    }
  };

  // ---------------- Phase A: per-(lane,q) min; lane owns pairs pr=k*64+lane --
  float m[QQ];
  #pragma unroll
  for (int q = 0; q < QQ; ++q) m[q] = INFINITY;
  #pragma unroll 1
  for (int i = 0; i < PIT; ++i) {
    f32x4 A0, B0, A1, B1;
    ldpair((2 * i + 0) * 64 + lane, A0, B0);
    ldpair((2 * i + 1) * 64 + lane, A1, B1);
    #pragma unroll
    for (int q = 0; q < QQ; ++q) {
      const f32x2 dA = __builtin_elementwise_fma(nxp[q], A0.xy,
                        __builtin_elementwise_fma(nyp[q], A0.zw,
                         __builtin_elementwise_fma(nzp[q], B0.xy, B0.zw)));
      const f32x2 dB = __builtin_elementwise_fma(nxp[q], A1.xy,
                        __builtin_elementwise_fma(nyp[q], A1.zw,
                         __builtin_elementwise_fma(nzp[q], B1.xy, B1.zw)));
      m[q] = fminf(fminf(m[q], fminf(dA.x, dA.y)), fminf(dB.x, dB.y));
    }
  }

  // ---- tau_q: 16-bit-PREFIX ballot bisection (validated r22). tau is the
  //      prefix ceiling >= exact 21st-smallest lane-min >= true tau. ----------
  float tau[QQ];
  #pragma unroll
  for (int q = 0; q < QQ; ++q) {
    const unsigned kp = fkey(m[q]) >> 16;
    unsigned lo = 0u, hi = 0xFFFFu;
    for (int b = 0; b < 16; ++b) {
      const unsigned mid = lo + ((hi - lo) >> 1);
      const unsigned long long bal = __ballot(kp <= mid);
      if (__popcll(bal) > KK) hi = mid; else lo = mid + 1;
    }
    tau[q] = fkey_inv((lo << 16) | 0xFFFFu);
  }

  // ---------------- Phase B: redistribute ACTIVE slices across lanes.
  //   Any candidate d<=tau[q] lies in a lane-slice with slice-min <= tau[q];
  //   ballot marks those (~21/q). Flatten the ~84 (q,slice) items; each lane
  //   decodes one item and scans that single slice (one q -> 4x fewer pk_fma
  //   and check-sites than the all-q rescan). Collected set is identical. ----
  {
    const unsigned long long b0 = __ballot(m[0] <= tau[0]);
    const unsigned long long b1 = __ballot(m[1] <= tau[1]);
    const unsigned long long b2 = __ballot(m[2] <= tau[2]);
    const unsigned long long b3 = __ballot(m[3] <= tau[3]);
    const int c0 = __popcll(b0);
    const int c1 = c0 + __popcll(b1);
    const int c2 = c1 + __popcll(b2);
    const int c3 = c2 + __popcll(b3);
    const int rounds = (c3 + 63) >> 6;

    #pragma unroll 1
    for (int rd = 0; rd < rounds; ++rd) {
      const int t = (rd << 6) + lane;
      if (t < c3) {
        // decode q (cum counts are wave-uniform) and rank r within ballot q
        const int q = (t >= c0) + (t >= c1) + (t >= c2);
        int r = t - (q == 0 ? 0 : (q == 1 ? c0 : (q == 2 ? c1 : c2)));
        unsigned long long bq = (q == 0) ? b0 : ((q == 1) ? b1 : ((q == 2) ? b2 : b3));
        // b = r-th set bit of bq (popc binary search, branch-free-ish)
        int b = 0;
        {
          int h = __popcll(bq & 0xFFFFFFFFull);
          if (r >= h) { b += 32; r -= h; bq >>= 32; }
          unsigned v = (unsigned)bq;
          h = __popc(v & 0xFFFFu); if (r >= h) { b += 16; r -= h; v >>= 16; }
          h = __popc(v & 0xFFu);   if (r >= h) { b += 8;  r -= h; v >>= 8;  }
          h = __popc(v & 0xFu);    if (r >= h) { b += 4;  r -= h; v >>= 4;  }
          h = __popc(v & 0x3u);    if (r >= h) { b += 2;  r -= h; v >>= 2;  }
          h = v & 1u;              if (r >= h) { b += 1; }
        }
        // select this item's coeffs / tau / row (compile-time indices only)
        const f32x2 cnx = (q & 2) ? ((q & 1) ? nxp[3] : nxp[2])
                                  : ((q & 1) ? nxp[1] : nxp[0]);
        const f32x2 cny = (q & 2) ? ((q & 1) ? nyp[3] : nyp[2])
                                  : ((q & 1) ? nyp[1] : nyp[0]);
        const f32x2 cnz = (q & 2) ? ((q & 1) ? nzp[3] : nzp[2])
                                  : ((q & 1) ? nzp[1] : nzp[0]);
        const float ct  = (q & 2) ? ((q & 1) ? tau[3] : tau[2])
                                  : ((q & 1) ? tau[1] : tau[0]);
        const int row = g0 + q;
        // scan slice b: pairs pr = k*64 + b, k = 0..31 (matches Phase A)
        #pragma unroll 1
        for (int k = 0; k < 32; k += 2) {
          const int pr0 = (k + 0) * 64 + b;
          const int pr1 = (k + 1) * 64 + b;
          f32x4 A0, B0, A1, B1;
          ldpair(pr0, A0, B0);
          ldpair(pr1, A1, B1);
          const f32x2 dA = __builtin_elementwise_fma(cnx, A0.xy,
                            __builtin_elementwise_fma(cny, A0.zw,
                             __builtin_elementwise_fma(cnz, B0.xy, B0.zw)));
          const f32x2 dB = __builtin_elementwise_fma(cnx, A1.xy,
                            __builtin_elementwise_fma(cny, A1.zw,
                             __builtin_elementwise_fma(cnz, B1.xy, B1.zw)));
          if (dA.x <= ct) { const int wp = atomicAdd(&pc[row], 1);
            if (wp < CAP) cand[row][wp] = make_float2(dA.x, __int_as_float(2 * pr0)); }
          if (dA.y <= ct) { const int wp = atomicAdd(&pc[row], 1);
            if (wp < CAP) cand[row][wp] = make_float2(dA.y, __int_as_float(2 * pr0 + 1)); }
          if (dB.x <= ct) { const int wp = atomicAdd(&pc[row], 1);
            if (wp < CAP) cand[row][wp] = make_float2(dB.x, __int_as_float(2 * pr1)); }
          if (dB.y <= ct) { const int wp = atomicAdd(&pc[row], 1);
            if (wp < CAP) cand[row][wp] = make_float2(dB.y, __int_as_float(2 * pr1 + 1)); }
        }
      }
    }
  }
  __syncthreads();

  // ---- Rank + compact: keep j != self with lex-rank(d, j) <= 20 (exactly 20;
  //      matches top_k's low-index tie-break; kept SET deterministic) ---------
  {
    const int g   = tid >> 4;            // 16 helper threads per point
    const int k0  = tid & 15;
    const int myp = blk * PPB + g;
    const int n0  = pc[g];
    const int n   = n0 < CAP ? n0 : CAP;
    for (int k = k0; k < n; k += 16) {
      const float2 ck = cand[g][k];
      const float dk = ck.x; const int jk = __float_as_int(ck.y);
      int rank = 0;
      for (int k2 = 0; k2 < n; ++k2) {
        const float2 c2 = cand[g][k2];
        rank += (c2.x < dk || (c2.x == dk && __float_as_int(c2.y) < jk)) ? 1 : 0;
      }
      if (jk != myp && rank <= KK) jkeep[g][atomicAdd(&pk[g], 1)] = jk;
    }
  }
  __syncthreads();

  // ---------------- Feature phase: lane = channel; h = xj.w345 + const_i -----
  const float w3 = W[3*64+lane], w4 = W[4*64+lane], w5 = W[5*64+lane];
  const float c0 = W[0*64+lane] - w3;
  const float c1 = W[1*64+lane] - w4;
  const float c2 = W[2*64+lane] - w5;
  const float bo = bias[lane];

  for (int pi = 0; pi < QQ; ++pi) {          // wave's own 4 points
    const int p   = g0 + pi;
    const int pid = blk * PPB + p;
    const float4 xi = ldp(pid);              // query point (plain index)
    const float ci = fmaf(xi.x, c0, fmaf(xi.y, c1, fmaf(xi.z, c2, bo)));
    float hmax = -INFINITY;
    #pragma unroll 5
    for (int k = 0; k < KK; ++k) {           // exactly 20, wave-uniform
      const int j = __builtin_amdgcn_readfirstlane(jkeep[p][k]);  // scalar path
      const float4 xp = ldp(j);
      hmax = fmaxf(hmax, fmaf(xp.x, w3, fmaf(xp.y, w4, fmaf(xp.z, w5, ci))));
    }
    out[(size_t)(base + pid) * 64 + lane] = fmaxf(hmax, 0.0f);
  }
}

extern "C" void kernel_launch(void* const* d_in, const int* in_sizes, int n_in,
                              void* d_out, int out_size, void* d_ws, size_t ws_size,
                              hipStream_t stream) {
  const float* x  = (const float*)d_in[0];
  // d_in[1] = batch (implicit: i / N) — unused
  const float* W  = (const float*)d_in[2];
  const float* b  = (const float*)d_in[3];
  float* out = (float*)d_out;

  const size_t aosz = (size_t)BB * NN * sizeof(float4);   // 512 KB
  const size_t need = 2 * aosz;                           // 1 MB
  dim3 grid(BB * BPB);   // 2048 blocks
  dim3 block(BLK);
  if (ws_size >= need) {
    float4* ws4 = (float4*)d_ws;
    f32x4* wspk = (f32x4*)((char*)d_ws + aosz);
    hipLaunchKernelGGL(prep_kernel, dim3(BB * NN / 2 / 256), dim3(256), 0, stream,
                       x, ws4, wspk);
    hipLaunchKernelGGL((edgeconv_kernel<true>), grid, block, 0, stream,
                       x, ws4, wspk, W, b, out);
  } else {
    hipLaunchKernelGGL((edgeconv_kernel<false>), grid, block, 0, stream,
                       x, (const float4*)nullptr, (const f32x4*)nullptr, W, b, out);
  }
}

// Round 24
// 70.664 us; speedup vs baseline: 1.3194x; 1.3194x over previous
//
#include <hip/hip_runtime.h>
#include <math.h>

#define NN    4096
#define KK    20
#define QQ    4                 // query points per lane (per wave)
#define WAVES 4
#define BLK   (WAVES*64)        // 256 threads
#define PPB   (WAVES*QQ)        // 16 points per block
#define PIT   16                // pair-iterations per phase (2 pairs/iter)
#define CAP   56                // per-point candidate capacity
#define BPB   (NN/PPB)          // 256 blocks per batch
#define BB    8

typedef float f32x4 __attribute__((ext_vector_type(4)));
typedef float f32x2 __attribute__((ext_vector_type(2)));

__device__ __forceinline__ unsigned fkey(float f) {  // monotone float->uint
  unsigned u = __float_as_uint(f);
  return u ^ ((unsigned)((int)u >> 31) | 0x80000000u);
}
__device__ __forceinline__ float fkey_inv(unsigned k) {
  unsigned u = (k & 0x80000000u) ? (k ^ 0x80000000u) : ~k;
  return __uint_as_float(u);
}

// one thread per point-PAIR: AoS table (feature) + pair-interleaved (scan)
__global__ void prep_kernel(const float* __restrict__ x,
                            float4* __restrict__ ws4,
                            f32x4* __restrict__ wspk) {
  const int p = blockIdx.x * 256 + threadIdx.x;        // 16384 pairs
  const float* s = x + (size_t)p * 6;
  const float x0 = s[0], y0 = s[1], z0 = s[2];
  const float x1 = s[3], y1 = s[4], z1 = s[5];
  const float w0 = fmaf(z0, z0, fmaf(y0, y0, x0 * x0));
  const float w1 = fmaf(z1, z1, fmaf(y1, y1, x1 * x1));
  ws4[2 * p]     = make_float4(x0, y0, z0, w0);
  ws4[2 * p + 1] = make_float4(x1, y1, z1, w1);
  wspk[2 * p]     = (f32x4){x0, x1, y0, y1};
  wspk[2 * p + 1] = (f32x4){z0, z1, w0, w1};
}

template<bool WS>
__global__ __launch_bounds__(BLK, 8)
void edgeconv_kernel(const float* __restrict__ x,
                     const float4* __restrict__ ws4,
                     const f32x4* __restrict__ wspk,
                     const float* __restrict__ W,
                     const float* __restrict__ bias,
                     float* __restrict__ out) {
  __shared__ float2 cand[PPB][CAP + 1];                // 7.3 KB (d, j-bits)
  __shared__ int    jkeep[PPB][21];                    // 1.3 KB
  __shared__ int    pc[PPB];
  __shared__ int    pk[PPB];

  const int tid  = threadIdx.x;
  const int lane = tid & 63;
  const int w    = tid >> 6;
  // batch-per-CU swizzle (validated r18/r22: FETCH 6.3 -> 1.0 MB)
  const int bb   = blockIdx.x % BB;
  const int blk  = blockIdx.x / BB;
  const int base = bb * NN;
  const int g0   = w * QQ;                 // wave's first point group
  const int myp0 = blk * PPB + g0;

  // packed query coeffs: d' = |xj|^2 - 2*xi.xj (order-preserving per point;
  // self value is the strict global minimum and rides along)
  f32x2 nxp[QQ], nyp[QQ], nzp[QQ];
  #pragma unroll
  for (int q = 0; q < QQ; ++q) {
    const float* p = x + (size_t)(base + myp0 + q) * 3;
    const float a = -2.f * p[0], b = -2.f * p[1], c = -2.f * p[2];
    nxp[q] = (f32x2){a, a}; nyp[q] = (f32x2){b, b}; nzp[q] = (f32x2){c, c};
  }

  if (tid < PPB) { pc[tid] = 0; pk[tid] = 0; }
  __syncthreads();

  // pair loader: A=(x0,x1,y0,y1), Bv=(z0,z1,w0,w1); identical fma chain in
  // both paths -> bit-identical d'
  auto ldpair = [&](int pr, f32x4& A, f32x4& Bv) {
    if constexpr (WS) {
      A  = wspk[base + (pr << 1)];
      Bv = wspk[base + (pr << 1) + 1];
    } else {
      const float* s = x + ((size_t)base + ((size_t)pr << 1)) * 3;
      const float x0 = s[0], y0 = s[1], z0 = s[2];
      const float x1 = s[3], y1 = s[4], z1 = s[5];
      A  = (f32x4){x0, x1, y0, y1};
      Bv = (f32x4){z0, z1, fmaf(z0, z0, fmaf(y0, y0, x0 * x0)),
                           fmaf(z1, z1, fmaf(y1, y1, x1 * x1))};
    }
  };
  // AoS point loader (feature phase)
  auto ldp = [&](int j) -> float4 {
    if constexpr (WS) {
      return ws4[base + j];
    } else {
      const float* p = x + (size_t)(base + j) * 3;
      const float a = p[0], b = p[1], c = p[2];
      return make_float4(a, b, c, fmaf(c, c, fmaf(b, b, a * a)));
    }
  };
  // packed distance: v_pk_fma_f32 chain via builtin (scheduler-visible)
  auto pdist = [&](int q, const f32x4& A, const f32x4& Bv) -> f32x2 {
    return __builtin_elementwise_fma(nxp[q], A.xy,
            __builtin_elementwise_fma(nyp[q], A.zw,
             __builtin_elementwise_fma(nzp[q], Bv.xy, Bv.zw)));
  };

  // ---------------- Phase A: per-(lane,q) min; lane owns pairs pr=i*64+lane.
  //   unroll 2: 8 independent loads + 48 pk_fma visible per scheduling window
  //   (compiler-managed liveness — no manual rotation, no spill pattern). ----
  float m[QQ];
  #pragma unroll
  for (int q = 0; q < QQ; ++q) m[q] = INFINITY;
  #pragma unroll 2
  for (int i = 0; i < PIT; ++i) {
    f32x4 A0, B0, A1, B1;
    ldpair((2 * i + 0) * 64 + lane, A0, B0);
    ldpair((2 * i + 1) * 64 + lane, A1, B1);
    #pragma unroll
    for (int q = 0; q < QQ; ++q) {
      const f32x2 dA = pdist(q, A0, B0);
      const f32x2 dB = pdist(q, A1, B1);
      m[q] = fminf(fminf(m[q], fminf(dA.x, dA.y)), fminf(dB.x, dB.y));
    }
  }

  // ---- tau_q: 16-bit-PREFIX ballot bisection (validated r22), with the 4
  //      q-chains INTERLEAVED: 4 independent serial ballot chains -> ~4x ILP
  //      on this memory-idle section. tau = prefix ceiling >= true tau. ------
  unsigned kp[QQ], lo[QQ], hi[QQ];
  #pragma unroll
  for (int q = 0; q < QQ; ++q) { kp[q] = fkey(m[q]) >> 16; lo[q] = 0u; hi[q] = 0xFFFFu; }
  for (int b = 0; b < 16; ++b) {
    #pragma unroll
    for (int q = 0; q < QQ; ++q) {
      const unsigned mid = lo[q] + ((hi[q] - lo[q]) >> 1);
      const unsigned long long bal = __ballot(kp[q] <= mid);
      if (__popcll(bal) > KK) hi[q] = mid; else lo[q] = mid + 1;
    }
  }
  float tau[QQ];
  #pragma unroll
  for (int q = 0; q < QQ; ++q) tau[q] = fkey_inv((lo[q] << 16) | 0xFFFFu);

  // ---------------- Phase B: collect candidates d' <= tau_q (self included);
  //                  flat per-element checks; byte-identical to r22 -----------
  #pragma unroll 1
  for (int i = 0; i < PIT; ++i) {
    const int pr0 = (2 * i + 0) * 64 + lane;
    const int pr1 = (2 * i + 1) * 64 + lane;
    f32x4 A0, B0, A1, B1;
    ldpair(pr0, A0, B0);
    ldpair(pr1, A1, B1);
    #pragma unroll
    for (int q = 0; q < QQ; ++q) {
      const f32x2 dA = pdist(q, A0, B0);
      const f32x2 dB = pdist(q, A1, B1);
      if (dA.x <= tau[q]) { const int wp = atomicAdd(&pc[g0 + q], 1);
        if (wp < CAP) cand[g0 + q][wp] = make_float2(dA.x, __int_as_float(2 * pr0)); }
      if (dA.y <= tau[q]) { const int wp = atomicAdd(&pc[g0 + q], 1);
        if (wp < CAP) cand[g0 + q][wp] = make_float2(dA.y, __int_as_float(2 * pr0 + 1)); }
      if (dB.x <= tau[q]) { const int wp = atomicAdd(&pc[g0 + q], 1);
        if (wp < CAP) cand[g0 + q][wp] = make_float2(dB.x, __int_as_float(2 * pr1)); }
      if (dB.y <= tau[q]) { const int wp = atomicAdd(&pc[g0 + q], 1);
        if (wp < CAP) cand[g0 + q][wp] = make_float2(dB.y, __int_as_float(2 * pr1 + 1)); }
    }
  }
  __syncthreads();

  // ---- Rank + compact: keep j != self with lex-rank(d, j) <= 20 (exactly 20;
  //      matches top_k's low-index tie-break; kept SET deterministic) ---------
  {
    const int g   = tid >> 4;            // 16 helper threads per point
    const int k0  = tid & 15;
    const int myp = blk * PPB + g;
    const int n0  = pc[g];
    const int n   = n0 < CAP ? n0 : CAP;
    for (int k = k0; k < n; k += 16) {
      const float2 ck = cand[g][k];
      const float dk = ck.x; const int jk = __float_as_int(ck.y);
      int rank = 0;
      for (int k2 = 0; k2 < n; ++k2) {
        const float2 c2 = cand[g][k2];
        rank += (c2.x < dk || (c2.x == dk && __float_as_int(c2.y) < jk)) ? 1 : 0;
      }
      if (jk != myp && rank <= KK) jkeep[g][atomicAdd(&pk[g], 1)] = jk;
    }
  }
  __syncthreads();

  // ---------------- Feature phase: lane = channel; h = xj.w345 + const_i -----
  const float w3 = W[3*64+lane], w4 = W[4*64+lane], w5 = W[5*64+lane];
  const float c0 = W[0*64+lane] - w3;
  const float c1 = W[1*64+lane] - w4;
  const float c2 = W[2*64+lane] - w5;
  const float bo = bias[lane];

  for (int pi = 0; pi < QQ; ++pi) {          // wave's own 4 points
    const int p   = g0 + pi;
    const int pid = blk * PPB + p;
    const float4 xi = ldp(pid);              // query point (plain index)
    const float ci = fmaf(xi.x, c0, fmaf(xi.y, c1, fmaf(xi.z, c2, bo)));
    float hmax = -INFINITY;
    #pragma unroll 5
    for (int k = 0; k < KK; ++k) {           // exactly 20, wave-uniform
      const int j = __builtin_amdgcn_readfirstlane(jkeep[p][k]);  // scalar path
      const float4 xp = ldp(j);
      hmax = fmaxf(hmax, fmaf(xp.x, w3, fmaf(xp.y, w4, fmaf(xp.z, w5, ci))));
    }
    out[(size_t)(base + pid) * 64 + lane] = fmaxf(hmax, 0.0f);
  }
}

extern "C" void kernel_launch(void* const* d_in, const int* in_sizes, int n_in,
                              void* d_out, int out_size, void* d_ws, size_t ws_size,
                              hipStream_t stream) {
  const float* x  = (const float*)d_in[0];
  // d_in[1] = batch (implicit: i / N) — unused
  const float* W  = (const float*)d_in[2];
  const float* b  = (const float*)d_in[3];
  float* out = (float*)d_out;

  const size_t aosz = (size_t)BB * NN * sizeof(float4);   // 512 KB
  const size_t need = 2 * aosz;                           // 1 MB
  dim3 grid(BB * BPB);   // 2048 blocks
  dim3 block(BLK);
  if (ws_size >= need) {
    float4* ws4 = (float4*)d_ws;
    f32x4* wspk = (f32x4*)((char*)d_ws + aosz);
    hipLaunchKernelGGL(prep_kernel, dim3(BB * NN / 2 / 256), dim3(256), 0, stream,
                       x, ws4, wspk);
    hipLaunchKernelGGL((edgeconv_kernel<true>), grid, block, 0, stream,
                       x, ws4, wspk, W, b, out);
  } else {
    hipLaunchKernelGGL((edgeconv_kernel<false>), grid, block, 0, stream,
                       x, (const float4*)nullptr, (const f32x4*)nullptr, W, b, out);
  }
}